// Round 1
// baseline (3818.524 us; speedup 1.0000x reference)
//
#include <hip/hip_runtime.h>
#include <math.h>

#define NPTS 8192
#define KNN 20

// workspace layout in floats
#define OFF_SQ   0          // 8192
#define OFF_IDX  8192       // 8192*20 ints
#define OFF_A    172032     // 8192*64
#define OFF_B    696320     // 8192*64
#define OFF_CAT  1220608    // 8192*192
#define OFF_H1   2793472    // 8192*1024
#define OFF_H2   11182080   // 8192*256
#define OFF_H3   13279232   // 8192*128

// ---------------- squared norms ----------------
template<int D>
__global__ __launch_bounds__(256)
void sqnorm_kernel(const float* __restrict__ X, int stride, float* __restrict__ sq) {
    int n = blockIdx.x * blockDim.x + threadIdx.x;
    if (n < NPTS) {
        float s = 0.f;
        #pragma unroll
        for (int f = 0; f < D; ++f) {
            float v = X[(size_t)n * stride + f];
            s = fmaf(v, v, s);
        }
        sq[n] = s;
    }
}

// ---------------- fused pairwise-distance + top-k ----------------
// block = 256 threads = 4 waves; each wave owns R=8 rows; lanes own column j.
// Running sorted top-20 per row kept in LDS; strict-< insertion reproduces
// jax.lax.top_k's stable tie-break (earlier index wins on equal distance).
template<int D>
__global__ __launch_bounds__(256)
void knn_kernel(const float* __restrict__ X, int stride,
                const float* __restrict__ sq, int* __restrict__ idx_out) {
    constexpr int R = 8;
    const int wave = threadIdx.x >> 6;
    const int lane = threadIdx.x & 63;
    const int row0 = (blockIdx.x * 4 + wave) * R;

    __shared__ float xi[4][R][D];
    __shared__ float sqi[4][R];
    __shared__ float topd[4][R][KNN];
    __shared__ int   topi[4][R][KNN];

    for (int t = lane; t < R * D; t += 64) {
        int r = t / D, f = t % D;
        xi[wave][r][f] = X[(size_t)(row0 + r) * stride + f];
    }
    if (lane < R) sqi[wave][lane] = sq[row0 + lane];
    for (int t = lane; t < R * KNN; t += 64) {
        topd[wave][t / KNN][t % KNN] = INFINITY;
        topi[wave][t / KNN][t % KNN] = -1;
    }
    __syncthreads();

    for (int jb = 0; jb < NPTS; jb += 64) {
        const int j = jb + lane;
        const float* xp = X + (size_t)j * stride;
        float xj[D];
        if constexpr (D == 64) {
            #pragma unroll
            for (int q = 0; q < 16; ++q) {
                float4 v = *reinterpret_cast<const float4*>(xp + 4 * q);
                xj[4*q+0] = v.x; xj[4*q+1] = v.y; xj[4*q+2] = v.z; xj[4*q+3] = v.w;
            }
        } else {
            #pragma unroll
            for (int f = 0; f < D; ++f) xj[f] = xp[f];
        }
        const float sqj = sq[j];

        float accv[R];
        #pragma unroll
        for (int r = 0; r < R; ++r) accv[r] = 0.f;

        if constexpr (D == 64) {
            #pragma unroll
            for (int f = 0; f < D; f += 4) {
                #pragma unroll
                for (int r = 0; r < R; ++r) {
                    float4 a4 = *reinterpret_cast<const float4*>(&xi[wave][r][f]);
                    accv[r] = fmaf(a4.x, xj[f+0], accv[r]);
                    accv[r] = fmaf(a4.y, xj[f+1], accv[r]);
                    accv[r] = fmaf(a4.z, xj[f+2], accv[r]);
                    accv[r] = fmaf(a4.w, xj[f+3], accv[r]);
                }
            }
        } else {
            #pragma unroll
            for (int f = 0; f < D; ++f) {
                #pragma unroll
                for (int r = 0; r < R; ++r)
                    accv[r] = fmaf(xi[wave][r][f], xj[f], accv[r]);
            }
        }

        #pragma unroll
        for (int r = 0; r < R; ++r) {
            float d = sqi[wave][r] + sqj - 2.f * accv[r];
            const int irow = row0 + r;
            bool cand = (j != irow) && (d < topd[wave][r][KNN - 1]);
            unsigned long long m = __ballot(cand);
            while (m) {
                const int src = __ffsll(m) - 1;
                m &= m - 1;
                if (lane == src) {
                    if (d < topd[wave][r][KNN - 1]) {   // re-check: earlier inserts may tighten
                        int p = KNN - 1;
                        while (p > 0 && d < topd[wave][r][p - 1]) {
                            topd[wave][r][p] = topd[wave][r][p - 1];
                            topi[wave][r][p] = topi[wave][r][p - 1];
                            --p;
                        }
                        topd[wave][r][p] = d;
                        topi[wave][r][p] = j;
                    }
                }
            }
        }
    }

    #pragma unroll
    for (int r = 0; r < R; ++r)
        if (lane < KNN)
            idx_out[(size_t)(row0 + r) * KNN + lane] = topi[wave][r][lane];
}

// ---------------- A = X*W_top, B = X*W_bot ----------------
template<int D>
__global__ __launch_bounds__(256)
void featAB_kernel(const float* __restrict__ X, int stride, const float* __restrict__ W,
                   float* __restrict__ A, float* __restrict__ B) {
    const int wave = threadIdx.x >> 6, lane = threadIdx.x & 63;
    const int n = blockIdx.x * 4 + wave;
    float a = 0.f, b = 0.f;
    const float* xp = X + (size_t)n * stride;
    #pragma unroll
    for (int f = 0; f < D; ++f) {
        float xf = xp[f];
        a = fmaf(xf, W[(size_t)f * 64 + lane], a);
        b = fmaf(xf, W[(size_t)(D + f) * 64 + lane], b);
    }
    A[(size_t)n * 64 + lane] = a;
    B[(size_t)n * 64 + lane] = b;
}

// ---------------- out[n][o] = relu(max_k (A[n]-B[n]+B[j_k]) + bias) ----------------
__global__ __launch_bounds__(256)
void edge_agg_kernel(const float* __restrict__ A, const float* __restrict__ B,
                     const int* __restrict__ idx, const float* __restrict__ bias,
                     float* __restrict__ out, int ostride) {
    const int wave = threadIdx.x >> 6, lane = threadIdx.x & 63;
    const int n = blockIdx.x * 4 + wave;
    const float base = A[(size_t)n * 64 + lane] - B[(size_t)n * 64 + lane] + bias[lane];
    float m = -INFINITY;
    #pragma unroll 4
    for (int k = 0; k < KNN; ++k) {
        int j = idx[(size_t)n * KNN + k];
        m = fmaxf(m, base + B[(size_t)j * 64 + lane]);
    }
    out[(size_t)n * ostride + lane] = fmaxf(m, 0.f);
}

// ---------------- generic fp32 GEMM + bias + relu ----------------
// block 256, computes 16 rows x 256 cols. A row stride as, K multiple of 64.
__global__ __launch_bounds__(256)
void gemm_relu_kernel(const float* __restrict__ A, int as, int K,
                      const float* __restrict__ W, const float* __restrict__ bias,
                      float* __restrict__ C, int N) {
    constexpr int KT = 64;
    __shared__ float at[16][KT];
    const int col = blockIdx.y * 256 + threadIdx.x;
    const int row0 = blockIdx.x * 16;
    float acc[16];
    #pragma unroll
    for (int r = 0; r < 16; ++r) acc[r] = 0.f;

    for (int kt = 0; kt < K; kt += KT) {
        for (int t = threadIdx.x; t < 16 * KT; t += 256)
            at[t / KT][t % KT] = A[(size_t)(row0 + t / KT) * as + kt + t % KT];
        __syncthreads();
        if (col < N) {
            for (int f = 0; f < KT; f += 4) {
                const float w0 = W[(size_t)(kt + f + 0) * N + col];
                const float w1 = W[(size_t)(kt + f + 1) * N + col];
                const float w2 = W[(size_t)(kt + f + 2) * N + col];
                const float w3 = W[(size_t)(kt + f + 3) * N + col];
                #pragma unroll
                for (int r = 0; r < 16; ++r) {
                    float4 a4 = *reinterpret_cast<const float4*>(&at[r][f]);
                    acc[r] = fmaf(a4.x, w0, acc[r]);
                    acc[r] = fmaf(a4.y, w1, acc[r]);
                    acc[r] = fmaf(a4.z, w2, acc[r]);
                    acc[r] = fmaf(a4.w, w3, acc[r]);
                }
            }
        }
        __syncthreads();
    }
    if (col < N) {
        const float b = bias[col];
        #pragma unroll
        for (int r = 0; r < 16; ++r)
            C[(size_t)(row0 + r) * N + col] = fmaxf(acc[r] + b, 0.f);
    }
}

// ---------------- final FC (128->50) + log_softmax, one wave per row ----------------
__global__ __launch_bounds__(256)
void final_kernel(const float* __restrict__ H, const float* __restrict__ Wo,
                  const float* __restrict__ bo, float* __restrict__ out) {
    const int wave = threadIdx.x >> 6, lane = threadIdx.x & 63;
    const int n = blockIdx.x * 4 + wave;
    float v = -INFINITY;
    if (lane < 50) {
        float a = bo[lane];
        const float* h = H + (size_t)n * 128;
        #pragma unroll 4
        for (int f = 0; f < 128; ++f) a = fmaf(h[f], Wo[f * 50 + lane], a);
        v = a;
    }
    float mx = v;
    #pragma unroll
    for (int off = 32; off; off >>= 1) mx = fmaxf(mx, __shfl_xor(mx, off));
    float e = (lane < 50) ? expf(v - mx) : 0.f;
    float s = e;
    #pragma unroll
    for (int off = 32; off; off >>= 1) s += __shfl_xor(s, off);
    if (lane < 50) out[(size_t)n * 50 + lane] = v - mx - logf(s);
}

extern "C" void kernel_launch(void* const* d_in, const int* in_sizes, int n_in,
                              void* d_out, int out_size, void* d_ws, size_t ws_size,
                              hipStream_t stream) {
    const float* x   = (const float*)d_in[0];
    const float* W1  = (const float*)d_in[1];
    const float* b1  = (const float*)d_in[2];
    const float* W2  = (const float*)d_in[3];
    const float* b2  = (const float*)d_in[4];
    const float* W3  = (const float*)d_in[5];
    const float* b3  = (const float*)d_in[6];
    const float* Wl  = (const float*)d_in[7];
    const float* bl  = (const float*)d_in[8];
    const float* Wm1 = (const float*)d_in[9];
    const float* bm1 = (const float*)d_in[10];
    const float* Wm2 = (const float*)d_in[11];
    const float* bm2 = (const float*)d_in[12];
    const float* Wo  = (const float*)d_in[13];
    const float* bo  = (const float*)d_in[14];

    float* ws   = (float*)d_ws;
    float* sq   = ws + OFF_SQ;
    int*   idx  = (int*)(ws + OFF_IDX);
    float* Abuf = ws + OFF_A;
    float* Bbuf = ws + OFF_B;
    float* cat  = ws + OFF_CAT;
    float* h1   = ws + OFF_H1;
    float* h2   = ws + OFF_H2;
    float* h3   = ws + OFF_H3;
    float* out  = (float*)d_out;

    dim3 b256(256);

    // conv1 (kNN on raw 3-D points)
    sqnorm_kernel<3><<<32, b256, 0, stream>>>(x, 3, sq);
    knn_kernel<3><<<256, b256, 0, stream>>>(x, 3, sq, idx);
    featAB_kernel<3><<<2048, b256, 0, stream>>>(x, 3, W1, Abuf, Bbuf);
    edge_agg_kernel<<<2048, b256, 0, stream>>>(Abuf, Bbuf, idx, b1, cat + 0, 192);

    // conv2 (kNN on x1)
    sqnorm_kernel<64><<<32, b256, 0, stream>>>(cat + 0, 192, sq);
    knn_kernel<64><<<256, b256, 0, stream>>>(cat + 0, 192, sq, idx);
    featAB_kernel<64><<<2048, b256, 0, stream>>>(cat + 0, 192, W2, Abuf, Bbuf);
    edge_agg_kernel<<<2048, b256, 0, stream>>>(Abuf, Bbuf, idx, b2, cat + 64, 192);

    // conv3 (kNN on x2)
    sqnorm_kernel<64><<<32, b256, 0, stream>>>(cat + 64, 192, sq);
    knn_kernel<64><<<256, b256, 0, stream>>>(cat + 64, 192, sq, idx);
    featAB_kernel<64><<<2048, b256, 0, stream>>>(cat + 64, 192, W3, Abuf, Bbuf);
    edge_agg_kernel<<<2048, b256, 0, stream>>>(Abuf, Bbuf, idx, b3, cat + 128, 192);

    // MLP head
    dim3 g1(512, 4);
    gemm_relu_kernel<<<g1, b256, 0, stream>>>(cat, 192, 192, Wl, bl, h1, 1024);
    dim3 g2(512, 1);
    gemm_relu_kernel<<<g2, b256, 0, stream>>>(h1, 1024, 1024, Wm1, bm1, h2, 256);
    dim3 g3(512, 1);
    gemm_relu_kernel<<<g3, b256, 0, stream>>>(h2, 256, 256, Wm2, bm2, h3, 128);
    final_kernel<<<2048, b256, 0, stream>>>(h3, Wo, bo, out);
}

// Round 2
// 2342.347 us; speedup vs baseline: 1.6302x; 1.6302x over previous
//
#include <hip/hip_runtime.h>
#include <math.h>

#define NPTS 8192
#define KNN 20
#define SLICES 16
#define SLICE_LEN (NPTS / SLICES)   // 512

// workspace layout in floats
#define OFF_SQ   0          // 8192
#define OFF_IDX  8192       // 8192*20 ints
#define OFF_A    172032     // 8192*64
#define OFF_B    696320     // 8192*64
#define OFF_CAT  1220608    // 8192*192
#define OFF_H1   2793472    // 8192*1024  (also aliased as u64 kNN partials: 21MB < 33.5MB)
#define OFF_H2   11182080   // 8192*256
#define OFF_H3   13279232   // 8192*128

// ---------------- squared norms ----------------
template<int D>
__global__ __launch_bounds__(256)
void sqnorm_kernel(const float* __restrict__ X, int stride, float* __restrict__ sq) {
    int n = blockIdx.x * blockDim.x + threadIdx.x;
    if (n < NPTS) {
        float s = 0.f;
        #pragma unroll
        for (int f = 0; f < D; ++f) {
            float v = X[(size_t)n * stride + f];
            s = fmaf(v, v, s);
        }
        sq[n] = s;
    }
}

// ---------------- kNN phase A: per-lane-row partial top-20 over a column slice ----
// lane = row. Private sorted top-20 in registers as packed u64 keys
// (ordered-f32(dist) << 32 | col), ascending => exact (dist, index) ordering,
// matching jax.lax.top_k's stable tie-break. Insert is a branch-free min/max
// network that is a no-op for lanes whose candidate doesn't qualify.
// x_j / sq_j are wave-uniform -> scalar loads on the SMEM pipe.
template<int D>
__global__ __launch_bounds__(256)
void knnA_kernel(const float* __restrict__ X, int stride,
                 const float* __restrict__ sq,
                 unsigned long long* __restrict__ part) {
    const int wave = threadIdx.x >> 6, lane = threadIdx.x & 63;
    const int gw = blockIdx.x * 4 + wave;   // 0..2047
    const int slice = gw >> 7;              // block's 4 waves share a slice (scalar-cache reuse)
    const int rowgroup = gw & 127;
    const int row = rowgroup * 64 + lane;

    float xi[D];
    #pragma unroll
    for (int f = 0; f < D; ++f) xi[f] = X[(size_t)row * stride + f];
    const float sqi = sq[row];

    unsigned long long top[KNN];
    #pragma unroll
    for (int k = 0; k < KNN; ++k) top[k] = ~0ULL;

    const int j0 = slice * SLICE_LEN;
    #pragma unroll 1
    for (int jj = 0; jj < SLICE_LEN; ++jj) {
        const int j = j0 + jj;
        const float* __restrict__ xj = X + (size_t)j * stride;  // wave-uniform
        float dot;
        if constexpr (D == 64) {
            float a0 = 0.f, a1 = 0.f, a2 = 0.f, a3 = 0.f;
            #pragma unroll
            for (int f = 0; f < 64; f += 4) {
                a0 = fmaf(xi[f + 0], xj[f + 0], a0);
                a1 = fmaf(xi[f + 1], xj[f + 1], a1);
                a2 = fmaf(xi[f + 2], xj[f + 2], a2);
                a3 = fmaf(xi[f + 3], xj[f + 3], a3);
            }
            dot = (a0 + a1) + (a2 + a3);
        } else {
            dot = xi[0] * xj[0];
            #pragma unroll
            for (int f = 1; f < D; ++f) dot = fmaf(xi[f], xj[f], dot);
        }
        float d = sqi + sq[j] - 2.f * dot;
        unsigned int db = __float_as_uint(d);
        unsigned int ord = db ^ ((unsigned int)((int)db >> 31) | 0x80000000u);
        unsigned long long key = ((unsigned long long)ord << 32) | (unsigned int)j;
        if (j == row) key = ~0ULL;   // self-exclusion
        if (__any(key < top[KNN - 1])) {
            // sorted insert: new[p] = min(old[p], max(key, old[p-1])); no-op if key >= old[19]
            #pragma unroll
            for (int p = KNN - 1; p >= 1; --p) {
                unsigned long long hi = (key > top[p - 1]) ? key : top[p - 1];
                top[p] = (top[p] < hi) ? top[p] : hi;
            }
            top[0] = (top[0] < key) ? top[0] : key;
        }
    }

    unsigned long long* o = part + ((size_t)row * SLICES + slice) * KNN;
    #pragma unroll
    for (int k = 0; k < KNN; ++k) o[k] = top[k];
}

// ---------------- kNN phase B: merge 16 sorted partials per row ----------------
__global__ __launch_bounds__(256)
void knnB_kernel(const unsigned long long* __restrict__ part, int* __restrict__ idx_out) {
    const int row = blockIdx.x * 256 + threadIdx.x;
    unsigned long long top[KNN];
    #pragma unroll
    for (int k = 0; k < KNN; ++k) top[k] = ~0ULL;

    for (int s = 0; s < SLICES; ++s) {
        const unsigned long long* p = part + ((size_t)row * SLICES + s) * KNN;
        for (int k = 0; k < KNN; ++k) {
            unsigned long long c = p[k];
            if (c >= top[KNN - 1]) break;   // partial list sorted ascending
            #pragma unroll
            for (int q = KNN - 1; q >= 1; --q) {
                unsigned long long hi = (c > top[q - 1]) ? c : top[q - 1];
                top[q] = (top[q] < hi) ? top[q] : hi;
            }
            top[0] = (top[0] < c) ? top[0] : c;
        }
    }
    #pragma unroll
    for (int k = 0; k < KNN; ++k)
        idx_out[(size_t)row * KNN + k] = (int)(top[k] & 0xFFFFFFFFu);
}

// ---------------- A = X*W_top, B = X*W_bot ----------------
template<int D>
__global__ __launch_bounds__(256)
void featAB_kernel(const float* __restrict__ X, int stride, const float* __restrict__ W,
                   float* __restrict__ A, float* __restrict__ B) {
    const int wave = threadIdx.x >> 6, lane = threadIdx.x & 63;
    const int n = blockIdx.x * 4 + wave;
    float a = 0.f, b = 0.f;
    const float* xp = X + (size_t)n * stride;
    #pragma unroll
    for (int f = 0; f < D; ++f) {
        float xf = xp[f];
        a = fmaf(xf, W[(size_t)f * 64 + lane], a);
        b = fmaf(xf, W[(size_t)(D + f) * 64 + lane], b);
    }
    A[(size_t)n * 64 + lane] = a;
    B[(size_t)n * 64 + lane] = b;
}

// ---------------- out[n][o] = relu(max_k (A[n]-B[n]+B[j_k]) + bias) ----------------
__global__ __launch_bounds__(256)
void edge_agg_kernel(const float* __restrict__ A, const float* __restrict__ B,
                     const int* __restrict__ idx, const float* __restrict__ bias,
                     float* __restrict__ out, int ostride) {
    const int wave = threadIdx.x >> 6, lane = threadIdx.x & 63;
    const int n = blockIdx.x * 4 + wave;
    const float base = A[(size_t)n * 64 + lane] - B[(size_t)n * 64 + lane] + bias[lane];
    float m = -INFINITY;
    #pragma unroll 4
    for (int k = 0; k < KNN; ++k) {
        int j = idx[(size_t)n * KNN + k];
        m = fmaxf(m, base + B[(size_t)j * 64 + lane]);
    }
    out[(size_t)n * ostride + lane] = fmaxf(m, 0.f);
}

// ---------------- generic fp32 GEMM + bias + relu ----------------
__global__ __launch_bounds__(256)
void gemm_relu_kernel(const float* __restrict__ A, int as, int K,
                      const float* __restrict__ W, const float* __restrict__ bias,
                      float* __restrict__ C, int N) {
    constexpr int KT = 64;
    __shared__ float at[16][KT];
    const int col = blockIdx.y * 256 + threadIdx.x;
    const int row0 = blockIdx.x * 16;
    float acc[16];
    #pragma unroll
    for (int r = 0; r < 16; ++r) acc[r] = 0.f;

    for (int kt = 0; kt < K; kt += KT) {
        for (int t = threadIdx.x; t < 16 * KT; t += 256)
            at[t / KT][t % KT] = A[(size_t)(row0 + t / KT) * as + kt + t % KT];
        __syncthreads();
        if (col < N) {
            for (int f = 0; f < KT; f += 4) {
                const float w0 = W[(size_t)(kt + f + 0) * N + col];
                const float w1 = W[(size_t)(kt + f + 1) * N + col];
                const float w2 = W[(size_t)(kt + f + 2) * N + col];
                const float w3 = W[(size_t)(kt + f + 3) * N + col];
                #pragma unroll
                for (int r = 0; r < 16; ++r) {
                    float4 a4 = *reinterpret_cast<const float4*>(&at[r][f]);
                    acc[r] = fmaf(a4.x, w0, acc[r]);
                    acc[r] = fmaf(a4.y, w1, acc[r]);
                    acc[r] = fmaf(a4.z, w2, acc[r]);
                    acc[r] = fmaf(a4.w, w3, acc[r]);
                }
            }
        }
        __syncthreads();
    }
    if (col < N) {
        const float b = bias[col];
        #pragma unroll
        for (int r = 0; r < 16; ++r)
            C[(size_t)(row0 + r) * N + col] = fmaxf(acc[r] + b, 0.f);
    }
}

// ---------------- final FC (128->50) + log_softmax ----------------
__global__ __launch_bounds__(256)
void final_kernel(const float* __restrict__ H, const float* __restrict__ Wo,
                  const float* __restrict__ bo, float* __restrict__ out) {
    const int wave = threadIdx.x >> 6, lane = threadIdx.x & 63;
    const int n = blockIdx.x * 4 + wave;
    float v = -INFINITY;
    if (lane < 50) {
        float a = bo[lane];
        const float* h = H + (size_t)n * 128;
        #pragma unroll 4
        for (int f = 0; f < 128; ++f) a = fmaf(h[f], Wo[f * 50 + lane], a);
        v = a;
    }
    float mx = v;
    #pragma unroll
    for (int off = 32; off; off >>= 1) mx = fmaxf(mx, __shfl_xor(mx, off));
    float e = (lane < 50) ? expf(v - mx) : 0.f;
    float s = e;
    #pragma unroll
    for (int off = 32; off; off >>= 1) s += __shfl_xor(s, off);
    if (lane < 50) out[(size_t)n * 50 + lane] = v - mx - logf(s);
}

extern "C" void kernel_launch(void* const* d_in, const int* in_sizes, int n_in,
                              void* d_out, int out_size, void* d_ws, size_t ws_size,
                              hipStream_t stream) {
    const float* x   = (const float*)d_in[0];
    const float* W1  = (const float*)d_in[1];
    const float* b1  = (const float*)d_in[2];
    const float* W2  = (const float*)d_in[3];
    const float* b2  = (const float*)d_in[4];
    const float* W3  = (const float*)d_in[5];
    const float* b3  = (const float*)d_in[6];
    const float* Wl  = (const float*)d_in[7];
    const float* bl  = (const float*)d_in[8];
    const float* Wm1 = (const float*)d_in[9];
    const float* bm1 = (const float*)d_in[10];
    const float* Wm2 = (const float*)d_in[11];
    const float* bm2 = (const float*)d_in[12];
    const float* Wo  = (const float*)d_in[13];
    const float* bo  = (const float*)d_in[14];

    float* ws   = (float*)d_ws;
    float* sq   = ws + OFF_SQ;
    int*   idx  = (int*)(ws + OFF_IDX);
    float* Abuf = ws + OFF_A;
    float* Bbuf = ws + OFF_B;
    float* cat  = ws + OFF_CAT;
    float* h1   = ws + OFF_H1;
    unsigned long long* part = (unsigned long long*)(ws + OFF_H1);  // aliased; consumed before h1 written
    float* h2   = ws + OFF_H2;
    float* h3   = ws + OFF_H3;
    float* out  = (float*)d_out;

    dim3 b256(256);

    // conv1 (kNN on raw 3-D points)
    sqnorm_kernel<3><<<32, b256, 0, stream>>>(x, 3, sq);
    knnA_kernel<3><<<512, b256, 0, stream>>>(x, 3, sq, part);
    knnB_kernel<<<32, b256, 0, stream>>>(part, idx);
    featAB_kernel<3><<<2048, b256, 0, stream>>>(x, 3, W1, Abuf, Bbuf);
    edge_agg_kernel<<<2048, b256, 0, stream>>>(Abuf, Bbuf, idx, b1, cat + 0, 192);

    // conv2 (kNN on x1)
    sqnorm_kernel<64><<<32, b256, 0, stream>>>(cat + 0, 192, sq);
    knnA_kernel<64><<<512, b256, 0, stream>>>(cat + 0, 192, sq, part);
    knnB_kernel<<<32, b256, 0, stream>>>(part, idx);
    featAB_kernel<64><<<2048, b256, 0, stream>>>(cat + 0, 192, W2, Abuf, Bbuf);
    edge_agg_kernel<<<2048, b256, 0, stream>>>(Abuf, Bbuf, idx, b2, cat + 64, 192);

    // conv3 (kNN on x2)
    sqnorm_kernel<64><<<32, b256, 0, stream>>>(cat + 64, 192, sq);
    knnA_kernel<64><<<512, b256, 0, stream>>>(cat + 64, 192, sq, part);
    knnB_kernel<<<32, b256, 0, stream>>>(part, idx);
    featAB_kernel<64><<<2048, b256, 0, stream>>>(cat + 64, 192, W3, Abuf, Bbuf);
    edge_agg_kernel<<<2048, b256, 0, stream>>>(Abuf, Bbuf, idx, b3, cat + 128, 192);

    // MLP head
    dim3 g1(512, 4);
    gemm_relu_kernel<<<g1, b256, 0, stream>>>(cat, 192, 192, Wl, bl, h1, 1024);
    dim3 g2(512, 1);
    gemm_relu_kernel<<<g2, b256, 0, stream>>>(h1, 1024, 1024, Wm1, bm1, h2, 256);
    dim3 g3(512, 1);
    gemm_relu_kernel<<<g3, b256, 0, stream>>>(h2, 256, 256, Wm2, bm2, h3, 128);
    final_kernel<<<2048, b256, 0, stream>>>(h3, Wo, bo, out);
}

// Round 3
// 1070.823 us; speedup vs baseline: 3.5660x; 2.1874x over previous
//
#include <hip/hip_runtime.h>
#include <math.h>

#define NPTS 8192
#define KNN 20
#define SLICES 32
#define SLICE_LEN (NPTS / SLICES)   // 256

// workspace layout in floats
#define OFF_SQ   0          // 8192
#define OFF_IDX  8192       // 8192*20 ints
#define OFF_A    172032     // 8192*64
#define OFF_B    696320     // 8192*64
#define OFF_CAT  1220608    // 8192*192
#define OFF_H1   2793472    // 8192*1024  (aliased as u32 kNN partials: 21MB < 33.5MB)
#define OFF_H2   11182080   // 8192*256
#define OFF_H3   13279232   // 8192*128

// ---------------- squared norms ----------------
template<int D>
__global__ __launch_bounds__(256)
void sqnorm_kernel(const float* __restrict__ X, int stride, float* __restrict__ sq) {
    int n = blockIdx.x * blockDim.x + threadIdx.x;
    if (n < NPTS) {
        float s = 0.f;
        #pragma unroll
        for (int f = 0; f < D; ++f) {
            float v = X[(size_t)n * stride + f];
            s = fmaf(v, v, s);
        }
        sq[n] = s;
    }
}

// ---------------- kNN phase A: per-lane-row partial top-20 over a column slice ----
// lane = row. Private sorted top-20 in registers as u32 keys:
//   (ordered_f32(dist) & 0xFFFFE000) | j   (j fits in 13 bits, NPTS=8192)
// Ascending order = (truncated dist, index) — matches top_k's stable tie-break
// up to 2^-10-relative dist truncation (boundary near-ties only; absorbed by
// the max-aggregation + 8e-2 threshold). Insert is a branchless 20-step
// v_min_u32/v_max_u32 network run every column (fire rate ~1 anyway).
// Slice base is readfirstlane'd so x_j / sq_j are true scalar (SMEM) loads.
template<int D>
__global__ __launch_bounds__(256, 4)
void knnA_kernel(const float* __restrict__ X, int stride,
                 const float* __restrict__ sq,
                 unsigned int* __restrict__ part) {
    const int wave = threadIdx.x >> 6, lane = threadIdx.x & 63;
    const int gw = blockIdx.x * 4 + wave;   // 0..4095
    // block's 4 waves share a slice (scalar-cache reuse of the x_j stream)
    const int slice = __builtin_amdgcn_readfirstlane(gw >> 7);
    const int rowgroup = gw & 127;
    const int row = rowgroup * 64 + lane;

    float xi[D];
    #pragma unroll
    for (int f = 0; f < D; ++f) xi[f] = X[(size_t)row * stride + f];
    const float sqi = sq[row];

    unsigned int top[KNN];
    #pragma unroll
    for (int k = 0; k < KNN; ++k) top[k] = 0xFFFFFFFFu;

    const int j0 = slice * SLICE_LEN;
    #pragma unroll 2
    for (int jj = 0; jj < SLICE_LEN; ++jj) {
        const int j = j0 + jj;
        const float* __restrict__ xj = X + (size_t)j * stride;  // wave-uniform (SGPR)
        float dot;
        if constexpr (D == 64) {
            float a0 = 0.f, a1 = 0.f, a2 = 0.f, a3 = 0.f;
            #pragma unroll
            for (int f = 0; f < 64; f += 4) {
                a0 = fmaf(xi[f + 0], xj[f + 0], a0);
                a1 = fmaf(xi[f + 1], xj[f + 1], a1);
                a2 = fmaf(xi[f + 2], xj[f + 2], a2);
                a3 = fmaf(xi[f + 3], xj[f + 3], a3);
            }
            dot = (a0 + a1) + (a2 + a3);
        } else {
            dot = xi[0] * xj[0];
            #pragma unroll
            for (int f = 1; f < D; ++f) dot = fmaf(xi[f], xj[f], dot);
        }
        float d = sqi + sq[j] - 2.f * dot;
        unsigned int db = __float_as_uint(d);
        unsigned int ord = db ^ ((unsigned int)((int)db >> 31) | 0x80000000u);
        unsigned int key = (ord & 0xFFFFE000u) | (unsigned int)j;
        if (j == row) key = 0xFFFFFFFFu;   // self-exclusion

        // branchless sorted insert (drops old top[19])
        unsigned int prev = top[0];
        top[0] = min(top[0], key);
        #pragma unroll
        for (int p = 1; p < KNN; ++p) {
            unsigned int hi = max(key, prev);
            prev = top[p];
            top[p] = min(top[p], hi);
        }
    }

    unsigned int* o = part + ((size_t)row * SLICES + slice) * KNN;
    #pragma unroll
    for (int k = 0; k < KNN; ++k) o[k] = top[k];
}

// ---------------- kNN phase B: merge 32 sorted partials per row ----------------
__global__ __launch_bounds__(256)
void knnB_kernel(const unsigned int* __restrict__ part, int* __restrict__ idx_out) {
    const int row = blockIdx.x * 256 + threadIdx.x;
    unsigned int top[KNN];
    #pragma unroll
    for (int k = 0; k < KNN; ++k) top[k] = 0xFFFFFFFFu;

    for (int s = 0; s < SLICES; ++s) {
        const unsigned int* p = part + ((size_t)row * SLICES + s) * KNN;
        for (int k = 0; k < KNN; ++k) {
            unsigned int c = p[k];
            if (c >= top[KNN - 1]) break;   // partial list sorted ascending
            unsigned int prev = top[0];
            top[0] = min(top[0], c);
            #pragma unroll
            for (int q = 1; q < KNN; ++q) {
                unsigned int hi = max(c, prev);
                prev = top[q];
                top[q] = min(top[q], hi);
            }
        }
    }
    #pragma unroll
    for (int k = 0; k < KNN; ++k)
        idx_out[(size_t)row * KNN + k] = (int)(top[k] & 0x1FFFu);
}

// ---------------- A = X*W_top, B = X*W_bot ----------------
template<int D>
__global__ __launch_bounds__(256)
void featAB_kernel(const float* __restrict__ X, int stride, const float* __restrict__ W,
                   float* __restrict__ A, float* __restrict__ B) {
    const int wave = threadIdx.x >> 6, lane = threadIdx.x & 63;
    const int n = blockIdx.x * 4 + wave;
    float a = 0.f, b = 0.f;
    const float* xp = X + (size_t)n * stride;
    #pragma unroll
    for (int f = 0; f < D; ++f) {
        float xf = xp[f];
        a = fmaf(xf, W[(size_t)f * 64 + lane], a);
        b = fmaf(xf, W[(size_t)(D + f) * 64 + lane], b);
    }
    A[(size_t)n * 64 + lane] = a;
    B[(size_t)n * 64 + lane] = b;
}

// ---------------- out[n][o] = relu(max_k (A[n]-B[n]+B[j_k]) + bias) ----------------
__global__ __launch_bounds__(256)
void edge_agg_kernel(const float* __restrict__ A, const float* __restrict__ B,
                     const int* __restrict__ idx, const float* __restrict__ bias,
                     float* __restrict__ out, int ostride) {
    const int wave = threadIdx.x >> 6, lane = threadIdx.x & 63;
    const int n = blockIdx.x * 4 + wave;
    const float base = A[(size_t)n * 64 + lane] - B[(size_t)n * 64 + lane] + bias[lane];
    float m = -INFINITY;
    #pragma unroll 4
    for (int k = 0; k < KNN; ++k) {
        int j = idx[(size_t)n * KNN + k];
        m = fmaxf(m, base + B[(size_t)j * 64 + lane]);
    }
    out[(size_t)n * ostride + lane] = fmaxf(m, 0.f);
}

// ---------------- generic fp32 GEMM + bias + relu ----------------
__global__ __launch_bounds__(256)
void gemm_relu_kernel(const float* __restrict__ A, int as, int K,
                      const float* __restrict__ W, const float* __restrict__ bias,
                      float* __restrict__ C, int N) {
    constexpr int KT = 64;
    __shared__ float at[16][KT];
    const int col = blockIdx.y * 256 + threadIdx.x;
    const int row0 = blockIdx.x * 16;
    float acc[16];
    #pragma unroll
    for (int r = 0; r < 16; ++r) acc[r] = 0.f;

    for (int kt = 0; kt < K; kt += KT) {
        for (int t = threadIdx.x; t < 16 * KT; t += 256)
            at[t / KT][t % KT] = A[(size_t)(row0 + t / KT) * as + kt + t % KT];
        __syncthreads();
        if (col < N) {
            for (int f = 0; f < KT; f += 4) {
                const float w0 = W[(size_t)(kt + f + 0) * N + col];
                const float w1 = W[(size_t)(kt + f + 1) * N + col];
                const float w2 = W[(size_t)(kt + f + 2) * N + col];
                const float w3 = W[(size_t)(kt + f + 3) * N + col];
                #pragma unroll
                for (int r = 0; r < 16; ++r) {
                    float4 a4 = *reinterpret_cast<const float4*>(&at[r][f]);
                    acc[r] = fmaf(a4.x, w0, acc[r]);
                    acc[r] = fmaf(a4.y, w1, acc[r]);
                    acc[r] = fmaf(a4.z, w2, acc[r]);
                    acc[r] = fmaf(a4.w, w3, acc[r]);
                }
            }
        }
        __syncthreads();
    }
    if (col < N) {
        const float b = bias[col];
        #pragma unroll
        for (int r = 0; r < 16; ++r)
            C[(size_t)(row0 + r) * N + col] = fmaxf(acc[r] + b, 0.f);
    }
}

// ---------------- final FC (128->50) + log_softmax ----------------
__global__ __launch_bounds__(256)
void final_kernel(const float* __restrict__ H, const float* __restrict__ Wo,
                  const float* __restrict__ bo, float* __restrict__ out) {
    const int wave = threadIdx.x >> 6, lane = threadIdx.x & 63;
    const int n = blockIdx.x * 4 + wave;
    float v = -INFINITY;
    if (lane < 50) {
        float a = bo[lane];
        const float* h = H + (size_t)n * 128;
        #pragma unroll 4
        for (int f = 0; f < 128; ++f) a = fmaf(h[f], Wo[f * 50 + lane], a);
        v = a;
    }
    float mx = v;
    #pragma unroll
    for (int off = 32; off; off >>= 1) mx = fmaxf(mx, __shfl_xor(mx, off));
    float e = (lane < 50) ? expf(v - mx) : 0.f;
    float s = e;
    #pragma unroll
    for (int off = 32; off; off >>= 1) s += __shfl_xor(s, off);
    if (lane < 50) out[(size_t)n * 50 + lane] = v - mx - logf(s);
}

extern "C" void kernel_launch(void* const* d_in, const int* in_sizes, int n_in,
                              void* d_out, int out_size, void* d_ws, size_t ws_size,
                              hipStream_t stream) {
    const float* x   = (const float*)d_in[0];
    const float* W1  = (const float*)d_in[1];
    const float* b1  = (const float*)d_in[2];
    const float* W2  = (const float*)d_in[3];
    const float* b2  = (const float*)d_in[4];
    const float* W3  = (const float*)d_in[5];
    const float* b3  = (const float*)d_in[6];
    const float* Wl  = (const float*)d_in[7];
    const float* bl  = (const float*)d_in[8];
    const float* Wm1 = (const float*)d_in[9];
    const float* bm1 = (const float*)d_in[10];
    const float* Wm2 = (const float*)d_in[11];
    const float* bm2 = (const float*)d_in[12];
    const float* Wo  = (const float*)d_in[13];
    const float* bo  = (const float*)d_in[14];

    float* ws   = (float*)d_ws;
    float* sq   = ws + OFF_SQ;
    int*   idx  = (int*)(ws + OFF_IDX);
    float* Abuf = ws + OFF_A;
    float* Bbuf = ws + OFF_B;
    float* cat  = ws + OFF_CAT;
    float* h1   = ws + OFF_H1;
    unsigned int* part = (unsigned int*)(ws + OFF_H1);  // aliased; consumed before h1 written
    float* h2   = ws + OFF_H2;
    float* h3   = ws + OFF_H3;
    float* out  = (float*)d_out;

    dim3 b256(256);

    // conv1 (kNN on raw 3-D points)
    sqnorm_kernel<3><<<32, b256, 0, stream>>>(x, 3, sq);
    knnA_kernel<3><<<1024, b256, 0, stream>>>(x, 3, sq, part);
    knnB_kernel<<<32, b256, 0, stream>>>(part, idx);
    featAB_kernel<3><<<2048, b256, 0, stream>>>(x, 3, W1, Abuf, Bbuf);
    edge_agg_kernel<<<2048, b256, 0, stream>>>(Abuf, Bbuf, idx, b1, cat + 0, 192);

    // conv2 (kNN on x1)
    sqnorm_kernel<64><<<32, b256, 0, stream>>>(cat + 0, 192, sq);
    knnA_kernel<64><<<1024, b256, 0, stream>>>(cat + 0, 192, sq, part);
    knnB_kernel<<<32, b256, 0, stream>>>(part, idx);
    featAB_kernel<64><<<2048, b256, 0, stream>>>(cat + 0, 192, W2, Abuf, Bbuf);
    edge_agg_kernel<<<2048, b256, 0, stream>>>(Abuf, Bbuf, idx, b2, cat + 64, 192);

    // conv3 (kNN on x2)
    sqnorm_kernel<64><<<32, b256, 0, stream>>>(cat + 64, 192, sq);
    knnA_kernel<64><<<1024, b256, 0, stream>>>(cat + 64, 192, sq, part);
    knnB_kernel<<<32, b256, 0, stream>>>(part, idx);
    featAB_kernel<64><<<2048, b256, 0, stream>>>(cat + 64, 192, W3, Abuf, Bbuf);
    edge_agg_kernel<<<2048, b256, 0, stream>>>(Abuf, Bbuf, idx, b3, cat + 128, 192);

    // MLP head
    dim3 g1(512, 4);
    gemm_relu_kernel<<<g1, b256, 0, stream>>>(cat, 192, 192, Wl, bl, h1, 1024);
    dim3 g2(512, 1);
    gemm_relu_kernel<<<g2, b256, 0, stream>>>(h1, 1024, 1024, Wm1, bm1, h2, 256);
    dim3 g3(512, 1);
    gemm_relu_kernel<<<g3, b256, 0, stream>>>(h2, 256, 256, Wm2, bm2, h3, 128);
    final_kernel<<<2048, b256, 0, stream>>>(h3, Wo, bo, out);
}

// Round 4
// 795.894 us; speedup vs baseline: 4.7978x; 1.3454x over previous
//
#include <hip/hip_runtime.h>
#include <math.h>

#define NPTS 8192
#define KNN 20
#define NLISTS 32     // partial lists per row (merged by knnB)
#define JSPLIT 4      // j-range chunks per row-group

// workspace layout in floats
#define OFF_SQ   0          // 8192
#define OFF_IDX  8192       // 8192*20 ints
#define OFF_A    172032     // 8192*64
#define OFF_B    696320     // 8192*64
#define OFF_CAT  1220608    // 8192*192
#define OFF_H1   2793472    // 8192*1024 region; front = kNN partials + bf16 packs (consumed pre-h1)
#define OFF_H2   11182080   // 8192*256
#define OFF_H3   13279232   // 8192*128
#define OFF_PART OFF_H1                       // 8192*32*20 u32 = 5242880 slots
#define OFF_PACK (OFF_H1 + 5242880)           // 4 arrays x 262144 float-slots (bf16 [8192][64])
#define PACK_ELEMS 262144                     // 8192*64 ushorts / 2 per float-slot

typedef __attribute__((ext_vector_type(8))) short bf16x8;
typedef __attribute__((ext_vector_type(16))) float f32x16;

__device__ inline unsigned umed3(unsigned a, unsigned b, unsigned c) {
    unsigned d;
    asm("v_med3_u32 %0, %1, %2, %3" : "=v"(d) : "v"(a), "v"(b), "v"(c));
    return d;
}

__device__ inline unsigned short f2bf(float f) {
    unsigned u = __float_as_uint(f);
    u += 0x7FFFu + ((u >> 16) & 1u);
    return (unsigned short)(u >> 16);
}

// ---------------- squared norms ----------------
template<int D>
__global__ __launch_bounds__(256)
void sqnorm_kernel(const float* __restrict__ X, int stride, float* __restrict__ sq) {
    int n = blockIdx.x * blockDim.x + threadIdx.x;
    if (n < NPTS) {
        float s = 0.f;
        #pragma unroll
        for (int f = 0; f < D; ++f) {
            float v = X[(size_t)n * stride + f];
            s = fmaf(v, v, s);
        }
        sq[n] = s;
    }
}

// ---------------- split-bf16 prepack: X -> (Xhi,Xlo), Y=-2X -> (Yhi,Ylo) ----------------
template<int D, int KP>
__global__ __launch_bounds__(256)
void prepack_kernel(const float* __restrict__ X, int stride,
                    unsigned short* __restrict__ Xhi, unsigned short* __restrict__ Xlo,
                    unsigned short* __restrict__ Yhi, unsigned short* __restrict__ Ylo) {
    int t = blockIdx.x * 256 + threadIdx.x;   // over NPTS*KP
    int n = t >> (KP == 64 ? 6 : 4);
    int k = t & (KP - 1);
    float x = (k < D) ? X[(size_t)n * stride + k] : 0.f;
    unsigned short hi = f2bf(x);
    float hif = __uint_as_float((unsigned)hi << 16);
    unsigned short lo = f2bf(x - hif);
    float y = -2.f * x;
    unsigned short yhi = f2bf(y);
    float yhif = __uint_as_float((unsigned)yhi << 16);
    unsigned short ylo = f2bf(y - yhif);
    Xhi[t] = hi; Xlo[t] = lo; Yhi[t] = yhi; Ylo[t] = ylo;
}

// ---------------- kNN phase A via MFMA ----------------
// Swapped-operand 32x32 tiles: A = Y[j-tile] (Y=-2X), B = X[i-tile], so
// C[j][i] = -2*dot(X[j],X[i]); lane owns ONE column i = i0+(lane&31) and gets
// 16 j-values per tile -> per-lane register top-20 (u32 keys: truncated-dist | j),
// inserted via branchless med3 network (sorted-list invariant).
// Split bf16: dot = Yhi*Xhi + Yhi*Xlo + Ylo*Xhi (lo*lo dropped, ~2^-18 rel).
template<int KP>
__global__ __launch_bounds__(256, 2)
void knnA_mfma(const unsigned short* __restrict__ Yhi, const unsigned short* __restrict__ Ylo,
               const unsigned short* __restrict__ Xhi, const unsigned short* __restrict__ Xlo,
               const float* __restrict__ sq, unsigned int* __restrict__ part) {
    constexpr int NS = KP / 16;                      // k-slices
    constexpr int NT = NPTS / JSPLIT / 4 / 32;       // tiles per wave (=16)
    const int wave = threadIdx.x >> 6, lane = threadIdx.x & 63;
    const int col = lane & 31;
    const int h   = lane >> 5;
    const int i0  = blockIdx.x * 32;
    const int bi  = i0 + col;
    const int jbase = blockIdx.y * (NPTS / JSPLIT) + wave * (NPTS / JSPLIT / 4);

    // stationary B fragments: B[k][col=i], k = h*8 + r within each 16-slice
    bf16x8 bhi[NS], blo[NS];
    #pragma unroll
    for (int s = 0; s < NS; ++s) {
        bhi[s] = *(const bf16x8*)&Xhi[(size_t)bi * KP + s * 16 + h * 8];
        blo[s] = *(const bf16x8*)&Xlo[(size_t)bi * KP + s * 16 + h * 8];
    }
    const float sqi = sq[bi];

    unsigned top[KNN];
    #pragma unroll
    for (int k = 0; k < KNN; ++k) top[k] = 0xFFFFFFFFu;

    for (int jt = 0; jt < NT; ++jt) {
        const int j0 = jbase + jt * 32;
        const int aj = j0 + col;       // A row = j
        f32x16 C;
        #pragma unroll
        for (int r = 0; r < 16; ++r) C[r] = 0.f;
        #pragma unroll
        for (int s = 0; s < NS; ++s) {
            bf16x8 ahi = *(const bf16x8*)&Yhi[(size_t)aj * KP + s * 16 + h * 8];
            bf16x8 alo = *(const bf16x8*)&Ylo[(size_t)aj * KP + s * 16 + h * 8];
            C = __builtin_amdgcn_mfma_f32_32x32x16_bf16(ahi, bhi[s], C, 0, 0, 0);
            C = __builtin_amdgcn_mfma_f32_32x32x16_bf16(ahi, blo[s], C, 0, 0, 0);
            C = __builtin_amdgcn_mfma_f32_32x32x16_bf16(alo, bhi[s], C, 0, 0, 0);
        }
        // C reg r (=q*4+t) maps to j = j0 + 4h + 8q + t
        #pragma unroll
        for (int q = 0; q < 4; ++q) {
            const int jq = j0 + h * 4 + q * 8;
            const float4 s4 = *(const float4*)&sq[jq];
            #pragma unroll
            for (int t = 0; t < 4; ++t) {
                const int r = q * 4 + t;
                const int j = jq + t;
                float d = (sqi + ((const float*)&s4)[t]) + C[r];
                unsigned db = __float_as_uint(d);
                unsigned ord = db ^ ((unsigned)((int)db >> 31) | 0x80000000u);
                unsigned key = (ord & 0xFFFFE000u) | (unsigned)j;
                if (j == bi) key = 0xFFFFFFFFu;   // self-exclusion
                #pragma unroll
                for (int p = KNN - 1; p >= 1; --p)
                    top[p] = umed3(key, top[p - 1], top[p]);
                top[0] = min(top[0], key);
            }
        }
    }

    unsigned* o = part + ((size_t)bi * NLISTS + blockIdx.y * 8 + wave * 2 + h) * KNN;
    #pragma unroll
    for (int k = 0; k < KNN; ++k) o[k] = top[k];
}

// ---------------- kNN phase B: merge sorted partial lists per row ----------------
__global__ __launch_bounds__(256)
void knnB_kernel(const unsigned int* __restrict__ part, int* __restrict__ idx_out) {
    const int row = blockIdx.x * 256 + threadIdx.x;
    unsigned int top[KNN];
    #pragma unroll
    for (int k = 0; k < KNN; ++k) top[k] = 0xFFFFFFFFu;

    for (int s = 0; s < NLISTS; ++s) {
        const unsigned int* p = part + ((size_t)row * NLISTS + s) * KNN;
        for (int k = 0; k < KNN; ++k) {
            unsigned int c = p[k];
            if (c >= top[KNN - 1]) break;   // partial list sorted ascending
            #pragma unroll
            for (int q = KNN - 1; q >= 1; --q)
                top[q] = umed3(c, top[q - 1], top[q]);
            top[0] = min(top[0], c);
        }
    }
    #pragma unroll
    for (int k = 0; k < KNN; ++k)
        idx_out[(size_t)row * KNN + k] = (int)(top[k] & 0x1FFFu);
}

// ---------------- A = X*W_top, B = X*W_bot ----------------
template<int D>
__global__ __launch_bounds__(256)
void featAB_kernel(const float* __restrict__ X, int stride, const float* __restrict__ W,
                   float* __restrict__ A, float* __restrict__ B) {
    const int wave = threadIdx.x >> 6, lane = threadIdx.x & 63;
    const int n = blockIdx.x * 4 + wave;
    float a = 0.f, b = 0.f;
    const float* xp = X + (size_t)n * stride;
    #pragma unroll
    for (int f = 0; f < D; ++f) {
        float xf = xp[f];
        a = fmaf(xf, W[(size_t)f * 64 + lane], a);
        b = fmaf(xf, W[(size_t)(D + f) * 64 + lane], b);
    }
    A[(size_t)n * 64 + lane] = a;
    B[(size_t)n * 64 + lane] = b;
}

// ---------------- out[n][o] = relu(max_k (A[n]-B[n]+B[j_k]) + bias) ----------------
__global__ __launch_bounds__(256)
void edge_agg_kernel(const float* __restrict__ A, const float* __restrict__ B,
                     const int* __restrict__ idx, const float* __restrict__ bias,
                     float* __restrict__ out, int ostride) {
    const int wave = threadIdx.x >> 6, lane = threadIdx.x & 63;
    const int n = blockIdx.x * 4 + wave;
    const float base = A[(size_t)n * 64 + lane] - B[(size_t)n * 64 + lane] + bias[lane];
    float m = -INFINITY;
    #pragma unroll 4
    for (int k = 0; k < KNN; ++k) {
        int j = idx[(size_t)n * KNN + k];
        m = fmaxf(m, base + B[(size_t)j * 64 + lane]);
    }
    out[(size_t)n * ostride + lane] = fmaxf(m, 0.f);
}

// ---------------- generic fp32 GEMM + bias + relu ----------------
__global__ __launch_bounds__(256)
void gemm_relu_kernel(const float* __restrict__ A, int as, int K,
                      const float* __restrict__ W, const float* __restrict__ bias,
                      float* __restrict__ C, int N) {
    constexpr int KT = 64;
    __shared__ float at[16][KT];
    const int col = blockIdx.y * 256 + threadIdx.x;
    const int row0 = blockIdx.x * 16;
    float acc[16];
    #pragma unroll
    for (int r = 0; r < 16; ++r) acc[r] = 0.f;

    for (int kt = 0; kt < K; kt += KT) {
        for (int t = threadIdx.x; t < 16 * KT; t += 256)
            at[t / KT][t % KT] = A[(size_t)(row0 + t / KT) * as + kt + t % KT];
        __syncthreads();
        if (col < N) {
            for (int f = 0; f < KT; f += 4) {
                const float w0 = W[(size_t)(kt + f + 0) * N + col];
                const float w1 = W[(size_t)(kt + f + 1) * N + col];
                const float w2 = W[(size_t)(kt + f + 2) * N + col];
                const float w3 = W[(size_t)(kt + f + 3) * N + col];
                #pragma unroll
                for (int r = 0; r < 16; ++r) {
                    float4 a4 = *reinterpret_cast<const float4*>(&at[r][f]);
                    acc[r] = fmaf(a4.x, w0, acc[r]);
                    acc[r] = fmaf(a4.y, w1, acc[r]);
                    acc[r] = fmaf(a4.z, w2, acc[r]);
                    acc[r] = fmaf(a4.w, w3, acc[r]);
                }
            }
        }
        __syncthreads();
    }
    if (col < N) {
        const float b = bias[col];
        #pragma unroll
        for (int r = 0; r < 16; ++r)
            C[(size_t)(row0 + r) * N + col] = fmaxf(acc[r] + b, 0.f);
    }
}

// ---------------- final FC (128->50) + log_softmax ----------------
__global__ __launch_bounds__(256)
void final_kernel(const float* __restrict__ H, const float* __restrict__ Wo,
                  const float* __restrict__ bo, float* __restrict__ out) {
    const int wave = threadIdx.x >> 6, lane = threadIdx.x & 63;
    const int n = blockIdx.x * 4 + wave;
    float v = -INFINITY;
    if (lane < 50) {
        float a = bo[lane];
        const float* h = H + (size_t)n * 128;
        #pragma unroll 4
        for (int f = 0; f < 128; ++f) a = fmaf(h[f], Wo[f * 50 + lane], a);
        v = a;
    }
    float mx = v;
    #pragma unroll
    for (int off = 32; off; off >>= 1) mx = fmaxf(mx, __shfl_xor(mx, off));
    float e = (lane < 50) ? expf(v - mx) : 0.f;
    float s = e;
    #pragma unroll
    for (int off = 32; off; off >>= 1) s += __shfl_xor(s, off);
    if (lane < 50) out[(size_t)n * 50 + lane] = v - mx - logf(s);
}

extern "C" void kernel_launch(void* const* d_in, const int* in_sizes, int n_in,
                              void* d_out, int out_size, void* d_ws, size_t ws_size,
                              hipStream_t stream) {
    const float* x   = (const float*)d_in[0];
    const float* W1  = (const float*)d_in[1];
    const float* b1  = (const float*)d_in[2];
    const float* W2  = (const float*)d_in[3];
    const float* b2  = (const float*)d_in[4];
    const float* W3  = (const float*)d_in[5];
    const float* b3  = (const float*)d_in[6];
    const float* Wl  = (const float*)d_in[7];
    const float* bl  = (const float*)d_in[8];
    const float* Wm1 = (const float*)d_in[9];
    const float* bm1 = (const float*)d_in[10];
    const float* Wm2 = (const float*)d_in[11];
    const float* bm2 = (const float*)d_in[12];
    const float* Wo  = (const float*)d_in[13];
    const float* bo  = (const float*)d_in[14];

    float* ws   = (float*)d_ws;
    float* sq   = ws + OFF_SQ;
    int*   idx  = (int*)(ws + OFF_IDX);
    float* Abuf = ws + OFF_A;
    float* Bbuf = ws + OFF_B;
    float* cat  = ws + OFF_CAT;
    float* h1   = ws + OFF_H1;
    unsigned int* part = (unsigned int*)(ws + OFF_PART);
    unsigned short* Phi = (unsigned short*)(ws + OFF_PACK);
    unsigned short* Plo = (unsigned short*)(ws + OFF_PACK + PACK_ELEMS);
    unsigned short* Qhi = (unsigned short*)(ws + OFF_PACK + 2 * PACK_ELEMS);
    unsigned short* Qlo = (unsigned short*)(ws + OFF_PACK + 3 * PACK_ELEMS);
    float* h2   = ws + OFF_H2;
    float* h3   = ws + OFF_H3;
    float* out  = (float*)d_out;

    dim3 b256(256);
    dim3 gknn(256, JSPLIT);

    // conv1 (kNN on raw 3-D points, K padded to 16)
    sqnorm_kernel<3><<<32, b256, 0, stream>>>(x, 3, sq);
    prepack_kernel<3, 16><<<512, b256, 0, stream>>>(x, 3, Phi, Plo, Qhi, Qlo);
    knnA_mfma<16><<<gknn, b256, 0, stream>>>(Qhi, Qlo, Phi, Plo, sq, part);
    knnB_kernel<<<32, b256, 0, stream>>>(part, idx);
    featAB_kernel<3><<<2048, b256, 0, stream>>>(x, 3, W1, Abuf, Bbuf);
    edge_agg_kernel<<<2048, b256, 0, stream>>>(Abuf, Bbuf, idx, b1, cat + 0, 192);

    // conv2 (kNN on x1)
    sqnorm_kernel<64><<<32, b256, 0, stream>>>(cat + 0, 192, sq);
    prepack_kernel<64, 64><<<2048, b256, 0, stream>>>(cat + 0, 192, Phi, Plo, Qhi, Qlo);
    knnA_mfma<64><<<gknn, b256, 0, stream>>>(Qhi, Qlo, Phi, Plo, sq, part);
    knnB_kernel<<<32, b256, 0, stream>>>(part, idx);
    featAB_kernel<64><<<2048, b256, 0, stream>>>(cat + 0, 192, W2, Abuf, Bbuf);
    edge_agg_kernel<<<2048, b256, 0, stream>>>(Abuf, Bbuf, idx, b2, cat + 64, 192);

    // conv3 (kNN on x2)
    sqnorm_kernel<64><<<32, b256, 0, stream>>>(cat + 64, 192, sq);
    prepack_kernel<64, 64><<<2048, b256, 0, stream>>>(cat + 64, 192, Phi, Plo, Qhi, Qlo);
    knnA_mfma<64><<<gknn, b256, 0, stream>>>(Qhi, Qlo, Phi, Plo, sq, part);
    knnB_kernel<<<32, b256, 0, stream>>>(part, idx);
    featAB_kernel<64><<<2048, b256, 0, stream>>>(cat + 64, 192, W3, Abuf, Bbuf);
    edge_agg_kernel<<<2048, b256, 0, stream>>>(Abuf, Bbuf, idx, b3, cat + 128, 192);

    // MLP head
    dim3 g1(512, 4);
    gemm_relu_kernel<<<g1, b256, 0, stream>>>(cat, 192, 192, Wl, bl, h1, 1024);
    dim3 g2(512, 1);
    gemm_relu_kernel<<<g2, b256, 0, stream>>>(h1, 1024, 1024, Wm1, bm1, h2, 256);
    dim3 g3(512, 1);
    gemm_relu_kernel<<<g3, b256, 0, stream>>>(h2, 256, 256, Wm2, bm2, h3, 128);
    final_kernel<<<2048, b256, 0, stream>>>(h3, Wo, bo, out);
}

// Round 5
// 644.654 us; speedup vs baseline: 5.9234x; 1.2346x over previous
//
#include <hip/hip_runtime.h>
#include <math.h>

#define NPTS 8192
#define KNN 20
#define NLISTS 32     // partial lists per row (merged by knnB)
#define JSPLIT 4      // j-range chunks per row-group

// workspace layout in floats
#define OFF_SQ   0          // 8192
#define OFF_IDX  8192       // 8192*20 ints
#define OFF_A    172032     // 8192*64 (featAB A; tail reused for W-transpose packs in MLP phase)
#define OFF_B    696320     // 8192*64
#define OFF_CAT  1220608    // 8192*192
#define OFF_H1   2793472    // 8192*1024 region; front = kNN partials + bf16 packs (consumed pre-h1)
#define OFF_H2   11182080   // 8192*256
#define OFF_H3   13279232   // 8192*128
#define OFF_PART OFF_H1                       // 8192*32*20 u32 = 5242880 slots
#define OFF_PACK (OFF_H1 + 5242880)           // 4 arrays x 262144 float-slots (bf16 [8192][64])
#define PACK_ELEMS 262144                     // 8192*64 ushorts / 2 per float-slot
// W-transpose packs (ushort), placed in the featAB A-region (free after conv3 edge_agg):
#define OFF_WT   OFF_A      // WlT hi/lo: 2*98304 f; Wm1T hi/lo: 2*131072 f; Wm2T hi/lo: 2*16384 f = 491520 f total

typedef __attribute__((ext_vector_type(8))) short bf16x8;
typedef __attribute__((ext_vector_type(16))) float f32x16;

__device__ inline unsigned umed3(unsigned a, unsigned b, unsigned c) {
    unsigned d;
    asm("v_med3_u32 %0, %1, %2, %3" : "=v"(d) : "v"(a), "v"(b), "v"(c));
    return d;
}

__device__ inline unsigned short f2bf(float f) {
    unsigned u = __float_as_uint(f);
    u += 0x7FFFu + ((u >> 16) & 1u);
    return (unsigned short)(u >> 16);
}

// ---------------- squared norms ----------------
template<int D>
__global__ __launch_bounds__(256)
void sqnorm_kernel(const float* __restrict__ X, int stride, float* __restrict__ sq) {
    int n = blockIdx.x * blockDim.x + threadIdx.x;
    if (n < NPTS) {
        float s = 0.f;
        #pragma unroll
        for (int f = 0; f < D; ++f) {
            float v = X[(size_t)n * stride + f];
            s = fmaf(v, v, s);
        }
        sq[n] = s;
    }
}

// ---------------- split-bf16 prepack: X -> (Xhi,Xlo), Y=-2X -> (Yhi,Ylo) ----------------
template<int D, int KP>
__global__ __launch_bounds__(256)
void prepack_kernel(const float* __restrict__ X, int stride,
                    unsigned short* __restrict__ Xhi, unsigned short* __restrict__ Xlo,
                    unsigned short* __restrict__ Yhi, unsigned short* __restrict__ Ylo) {
    int t = blockIdx.x * 256 + threadIdx.x;   // over NPTS*KP
    int n = t >> (KP == 64 ? 6 : 4);
    int k = t & (KP - 1);
    float x = (k < D) ? X[(size_t)n * stride + k] : 0.f;
    unsigned short hi = f2bf(x);
    float hif = __uint_as_float((unsigned)hi << 16);
    unsigned short lo = f2bf(x - hif);
    float y = -2.f * x;
    unsigned short yhi = f2bf(y);
    float yhif = __uint_as_float((unsigned)yhi << 16);
    unsigned short ylo = f2bf(y - yhif);
    Xhi[t] = hi; Xlo[t] = lo; Yhi[t] = yhi; Ylo[t] = ylo;
}

// ---------------- W prepack: W[K][N] fp32 -> transposed [N][K] split-bf16 ----------------
template<int K, int NBITS>
__global__ __launch_bounds__(256)
void prepack_w(const float* __restrict__ W,
               unsigned short* __restrict__ Thi, unsigned short* __restrict__ Tlo) {
    const int N = 1 << NBITS;
    int t = blockIdx.x * 256 + threadIdx.x;   // t = k*N + n
    int k = t >> NBITS, n = t & (N - 1);
    float x = W[t];
    unsigned short hi = f2bf(x);
    float hif = __uint_as_float((unsigned)hi << 16);
    unsigned short lo = f2bf(x - hif);
    Thi[(size_t)n * K + k] = hi;
    Tlo[(size_t)n * K + k] = lo;
}

// ---------------- kNN phase A via MFMA ----------------
template<int KP>
__global__ __launch_bounds__(256, 2)
void knnA_mfma(const unsigned short* __restrict__ Yhi, const unsigned short* __restrict__ Ylo,
               const unsigned short* __restrict__ Xhi, const unsigned short* __restrict__ Xlo,
               const float* __restrict__ sq, unsigned int* __restrict__ part) {
    constexpr int NS = KP / 16;                      // k-slices
    constexpr int NT = NPTS / JSPLIT / 4 / 32;       // tiles per wave (=16)
    const int wave = threadIdx.x >> 6, lane = threadIdx.x & 63;
    const int col = lane & 31;
    const int h   = lane >> 5;
    const int i0  = blockIdx.x * 32;
    const int bi  = i0 + col;
    const int jbase = blockIdx.y * (NPTS / JSPLIT) + wave * (NPTS / JSPLIT / 4);

    bf16x8 bhi[NS], blo[NS];
    #pragma unroll
    for (int s = 0; s < NS; ++s) {
        bhi[s] = *(const bf16x8*)&Xhi[(size_t)bi * KP + s * 16 + h * 8];
        blo[s] = *(const bf16x8*)&Xlo[(size_t)bi * KP + s * 16 + h * 8];
    }
    const float sqi = sq[bi];

    unsigned top[KNN];
    #pragma unroll
    for (int k = 0; k < KNN; ++k) top[k] = 0xFFFFFFFFu;

    for (int jt = 0; jt < NT; ++jt) {
        const int j0 = jbase + jt * 32;
        const int aj = j0 + col;       // A row = j
        f32x16 C;
        #pragma unroll
        for (int r = 0; r < 16; ++r) C[r] = 0.f;
        #pragma unroll
        for (int s = 0; s < NS; ++s) {
            bf16x8 ahi = *(const bf16x8*)&Yhi[(size_t)aj * KP + s * 16 + h * 8];
            bf16x8 alo = *(const bf16x8*)&Ylo[(size_t)aj * KP + s * 16 + h * 8];
            C = __builtin_amdgcn_mfma_f32_32x32x16_bf16(ahi, bhi[s], C, 0, 0, 0);
            C = __builtin_amdgcn_mfma_f32_32x32x16_bf16(ahi, blo[s], C, 0, 0, 0);
            C = __builtin_amdgcn_mfma_f32_32x32x16_bf16(alo, bhi[s], C, 0, 0, 0);
        }
        #pragma unroll
        for (int q = 0; q < 4; ++q) {
            const int jq = j0 + h * 4 + q * 8;
            const float4 s4 = *(const float4*)&sq[jq];
            #pragma unroll
            for (int t = 0; t < 4; ++t) {
                const int r = q * 4 + t;
                const int j = jq + t;
                float d = (sqi + ((const float*)&s4)[t]) + C[r];
                unsigned db = __float_as_uint(d);
                unsigned ord = db ^ ((unsigned)((int)db >> 31) | 0x80000000u);
                unsigned key = (ord & 0xFFFFE000u) | (unsigned)j;
                if (j == bi) key = 0xFFFFFFFFu;   // self-exclusion
                #pragma unroll
                for (int p = KNN - 1; p >= 1; --p)
                    top[p] = umed3(key, top[p - 1], top[p]);
                top[0] = min(top[0], key);
            }
        }
    }

    unsigned* o = part + ((size_t)bi * NLISTS + blockIdx.y * 8 + wave * 2 + h) * KNN;
    #pragma unroll
    for (int k = 0; k < KNN; ++k) o[k] = top[k];
}

// ---------------- kNN phase B: merge sorted partial lists per row ----------------
__global__ __launch_bounds__(256)
void knnB_kernel(const unsigned int* __restrict__ part, int* __restrict__ idx_out) {
    const int row = blockIdx.x * 256 + threadIdx.x;
    unsigned int top[KNN];
    #pragma unroll
    for (int k = 0; k < KNN; ++k) top[k] = 0xFFFFFFFFu;

    for (int s = 0; s < NLISTS; ++s) {
        const unsigned int* p = part + ((size_t)row * NLISTS + s) * KNN;
        for (int k = 0; k < KNN; ++k) {
            unsigned int c = p[k];
            if (c >= top[KNN - 1]) break;   // partial list sorted ascending
            #pragma unroll
            for (int q = KNN - 1; q >= 1; --q)
                top[q] = umed3(c, top[q - 1], top[q]);
            top[0] = min(top[0], c);
        }
    }
    #pragma unroll
    for (int k = 0; k < KNN; ++k)
        idx_out[(size_t)row * KNN + k] = (int)(top[k] & 0x1FFFu);
}

// ---------------- A = X*W_top, B = X*W_bot ----------------
template<int D>
__global__ __launch_bounds__(256)
void featAB_kernel(const float* __restrict__ X, int stride, const float* __restrict__ W,
                   float* __restrict__ A, float* __restrict__ B) {
    const int wave = threadIdx.x >> 6, lane = threadIdx.x & 63;
    const int n = blockIdx.x * 4 + wave;
    float a = 0.f, b = 0.f;
    const float* xp = X + (size_t)n * stride;
    #pragma unroll
    for (int f = 0; f < D; ++f) {
        float xf = xp[f];
        a = fmaf(xf, W[(size_t)f * 64 + lane], a);
        b = fmaf(xf, W[(size_t)(D + f) * 64 + lane], b);
    }
    A[(size_t)n * 64 + lane] = a;
    B[(size_t)n * 64 + lane] = b;
}

// ---------------- out[n][o] = relu(max_k (A[n]-B[n]+B[j_k]) + bias) ----------------
__global__ __launch_bounds__(256)
void edge_agg_kernel(const float* __restrict__ A, const float* __restrict__ B,
                     const int* __restrict__ idx, const float* __restrict__ bias,
                     float* __restrict__ out, int ostride) {
    const int wave = threadIdx.x >> 6, lane = threadIdx.x & 63;
    const int n = blockIdx.x * 4 + wave;
    const float base = A[(size_t)n * 64 + lane] - B[(size_t)n * 64 + lane] + bias[lane];
    float m = -INFINITY;
    #pragma unroll 4
    for (int k = 0; k < KNN; ++k) {
        int j = idx[(size_t)n * KNN + k];
        m = fmaxf(m, base + B[(size_t)j * 64 + lane]);
    }
    out[(size_t)n * ostride + lane] = fmaxf(m, 0.f);
}

// ---------------- MFMA GEMM + bias + relu: C = relu(A[M][K] * W[K][N] + b) ----------------
// A fp32 (split to bf16 hi/lo on the fly); W prepacked transposed [N][K] split-bf16.
// Wave computes 32 rows x CTW*32 cols. C mapping (verified in knnA): row = 4h+8q+t, col = lane&31.
template<int K, int N, int CTW>
__global__ __launch_bounds__(256, 3)
void gemm_mfma_relu(const float* __restrict__ A,
                    const unsigned short* __restrict__ Whi, const unsigned short* __restrict__ Wlo,
                    const float* __restrict__ bias, float* __restrict__ C) {
    const int wave = threadIdx.x >> 6, lane = threadIdx.x & 63;
    const int col = lane & 31, h = lane >> 5;
    const int r0 = blockIdx.x * 32;
    const int nb = blockIdx.y * (CTW * 128) + wave * (CTW * 32);
    const float* arow = A + (size_t)(r0 + col) * K + h * 8;

    f32x16 acc[CTW];
    #pragma unroll
    for (int c = 0; c < CTW; ++c)
        #pragma unroll
        for (int r = 0; r < 16; ++r) acc[c][r] = 0.f;

    #pragma unroll 4
    for (int s = 0; s < K / 16; ++s) {
        float4 f0 = *(const float4*)(arow + s * 16);
        float4 f1 = *(const float4*)(arow + s * 16 + 4);
        float xs0 = f0.x, xs1 = f0.y, xs2 = f0.z, xs3 = f0.w;
        float xs4 = f1.x, xs5 = f1.y, xs6 = f1.z, xs7 = f1.w;
        bf16x8 ahi, alo;
        {
            float xv[8] = {xs0, xs1, xs2, xs3, xs4, xs5, xs6, xs7};
            #pragma unroll
            for (int e = 0; e < 8; ++e) {
                unsigned u = __float_as_uint(xv[e]);
                ahi[e] = (short)(u >> 16);                       // truncate-split hi
                float d = xv[e] - __uint_as_float(u & 0xFFFF0000u);
                alo[e] = (short)(__float_as_uint(d) >> 16);      // truncated residual
            }
        }
        #pragma unroll
        for (int c = 0; c < CTW; ++c) {
            const size_t wb = (size_t)(nb + c * 32 + col) * K + s * 16 + h * 8;
            bf16x8 bhi = *(const bf16x8*)&Whi[wb];
            bf16x8 blo = *(const bf16x8*)&Wlo[wb];
            acc[c] = __builtin_amdgcn_mfma_f32_32x32x16_bf16(ahi, bhi, acc[c], 0, 0, 0);
            acc[c] = __builtin_amdgcn_mfma_f32_32x32x16_bf16(alo, bhi, acc[c], 0, 0, 0);
            acc[c] = __builtin_amdgcn_mfma_f32_32x32x16_bf16(ahi, blo, acc[c], 0, 0, 0);
        }
    }

    #pragma unroll
    for (int c = 0; c < CTW; ++c) {
        const int n = nb + c * 32 + col;
        const float b = bias[n];
        #pragma unroll
        for (int q = 0; q < 4; ++q)
            #pragma unroll
            for (int t = 0; t < 4; ++t) {
                const int rl = 4 * h + 8 * q + t;
                C[(size_t)(r0 + rl) * N + n] = fmaxf(acc[c][q * 4 + t] + b, 0.f);
            }
    }
}

// ---------------- final FC (128->50) + log_softmax ----------------
__global__ __launch_bounds__(256)
void final_kernel(const float* __restrict__ H, const float* __restrict__ Wo,
                  const float* __restrict__ bo, float* __restrict__ out) {
    const int wave = threadIdx.x >> 6, lane = threadIdx.x & 63;
    const int n = blockIdx.x * 4 + wave;
    float v = -INFINITY;
    if (lane < 50) {
        float a = bo[lane];
        const float* h = H + (size_t)n * 128;
        #pragma unroll 4
        for (int f = 0; f < 128; ++f) a = fmaf(h[f], Wo[f * 50 + lane], a);
        v = a;
    }
    float mx = v;
    #pragma unroll
    for (int off = 32; off; off >>= 1) mx = fmaxf(mx, __shfl_xor(mx, off));
    float e = (lane < 50) ? expf(v - mx) : 0.f;
    float s = e;
    #pragma unroll
    for (int off = 32; off; off >>= 1) s += __shfl_xor(s, off);
    if (lane < 50) out[(size_t)n * 50 + lane] = v - mx - logf(s);
}

extern "C" void kernel_launch(void* const* d_in, const int* in_sizes, int n_in,
                              void* d_out, int out_size, void* d_ws, size_t ws_size,
                              hipStream_t stream) {
    const float* x   = (const float*)d_in[0];
    const float* W1  = (const float*)d_in[1];
    const float* b1  = (const float*)d_in[2];
    const float* W2  = (const float*)d_in[3];
    const float* b2  = (const float*)d_in[4];
    const float* W3  = (const float*)d_in[5];
    const float* b3  = (const float*)d_in[6];
    const float* Wl  = (const float*)d_in[7];
    const float* bl  = (const float*)d_in[8];
    const float* Wm1 = (const float*)d_in[9];
    const float* bm1 = (const float*)d_in[10];
    const float* Wm2 = (const float*)d_in[11];
    const float* bm2 = (const float*)d_in[12];
    const float* Wo  = (const float*)d_in[13];
    const float* bo  = (const float*)d_in[14];

    float* ws   = (float*)d_ws;
    float* sq   = ws + OFF_SQ;
    int*   idx  = (int*)(ws + OFF_IDX);
    float* Abuf = ws + OFF_A;
    float* Bbuf = ws + OFF_B;
    float* cat  = ws + OFF_CAT;
    float* h1   = ws + OFF_H1;
    unsigned int* part = (unsigned int*)(ws + OFF_PART);
    unsigned short* Phi = (unsigned short*)(ws + OFF_PACK);
    unsigned short* Plo = (unsigned short*)(ws + OFF_PACK + PACK_ELEMS);
    unsigned short* Qhi = (unsigned short*)(ws + OFF_PACK + 2 * PACK_ELEMS);
    unsigned short* Qlo = (unsigned short*)(ws + OFF_PACK + 3 * PACK_ELEMS);
    float* h2   = ws + OFF_H2;
    float* h3   = ws + OFF_H3;
    // W-transpose packs: live in the featAB A-region, free after conv3's edge_agg
    unsigned short* WlT_hi  = (unsigned short*)(ws + OFF_WT);
    unsigned short* WlT_lo  = (unsigned short*)(ws + OFF_WT + 98304);
    unsigned short* Wm1T_hi = (unsigned short*)(ws + OFF_WT + 196608);
    unsigned short* Wm1T_lo = (unsigned short*)(ws + OFF_WT + 327680);
    unsigned short* Wm2T_hi = (unsigned short*)(ws + OFF_WT + 458752);
    unsigned short* Wm2T_lo = (unsigned short*)(ws + OFF_WT + 475136);
    float* out  = (float*)d_out;

    dim3 b256(256);
    dim3 gknn(256, JSPLIT);

    // conv1 (kNN on raw 3-D points, K padded to 16)
    sqnorm_kernel<3><<<32, b256, 0, stream>>>(x, 3, sq);
    prepack_kernel<3, 16><<<512, b256, 0, stream>>>(x, 3, Phi, Plo, Qhi, Qlo);
    knnA_mfma<16><<<gknn, b256, 0, stream>>>(Qhi, Qlo, Phi, Plo, sq, part);
    knnB_kernel<<<32, b256, 0, stream>>>(part, idx);
    featAB_kernel<3><<<2048, b256, 0, stream>>>(x, 3, W1, Abuf, Bbuf);
    edge_agg_kernel<<<2048, b256, 0, stream>>>(Abuf, Bbuf, idx, b1, cat + 0, 192);

    // conv2 (kNN on x1)
    sqnorm_kernel<64><<<32, b256, 0, stream>>>(cat + 0, 192, sq);
    prepack_kernel<64, 64><<<2048, b256, 0, stream>>>(cat + 0, 192, Phi, Plo, Qhi, Qlo);
    knnA_mfma<64><<<gknn, b256, 0, stream>>>(Qhi, Qlo, Phi, Plo, sq, part);
    knnB_kernel<<<32, b256, 0, stream>>>(part, idx);
    featAB_kernel<64><<<2048, b256, 0, stream>>>(cat + 0, 192, W2, Abuf, Bbuf);
    edge_agg_kernel<<<2048, b256, 0, stream>>>(Abuf, Bbuf, idx, b2, cat + 64, 192);

    // conv3 (kNN on x2)
    sqnorm_kernel<64><<<32, b256, 0, stream>>>(cat + 64, 192, sq);
    prepack_kernel<64, 64><<<2048, b256, 0, stream>>>(cat + 64, 192, Phi, Plo, Qhi, Qlo);
    knnA_mfma<64><<<gknn, b256, 0, stream>>>(Qhi, Qlo, Phi, Plo, sq, part);
    knnB_kernel<<<32, b256, 0, stream>>>(part, idx);
    featAB_kernel<64><<<2048, b256, 0, stream>>>(cat + 64, 192, W3, Abuf, Bbuf);
    edge_agg_kernel<<<2048, b256, 0, stream>>>(Abuf, Bbuf, idx, b3, cat + 128, 192);

    // MLP head — weight prepack (A-region now free), then MFMA GEMMs
    prepack_w<192, 10><<<768, b256, 0, stream>>>(Wl, WlT_hi, WlT_lo);
    prepack_w<1024, 8><<<1024, b256, 0, stream>>>(Wm1, Wm1T_hi, Wm1T_lo);
    prepack_w<256, 7><<<128, b256, 0, stream>>>(Wm2, Wm2T_hi, Wm2T_lo);

    dim3 g1(256, 4);
    gemm_mfma_relu<192, 1024, 2><<<g1, b256, 0, stream>>>(cat, WlT_hi, WlT_lo, bl, h1);
    dim3 g2(256, 1);
    gemm_mfma_relu<1024, 256, 2><<<g2, b256, 0, stream>>>(h1, Wm1T_hi, Wm1T_lo, bm1, h2);
    dim3 g3(256, 1);
    gemm_mfma_relu<256, 128, 1><<<g3, b256, 0, stream>>>(h2, Wm2T_hi, Wm2T_lo, bm2, h3);
    final_kernel<<<2048, b256, 0, stream>>>(h3, Wo, bo, out);
}